// Round 3
// baseline (250.800 us; speedup 1.0000x reference)
//
#include <hip/hip_runtime.h>
#include <hip/hip_cooperative_groups.h>

namespace cg = cooperative_groups;

#define CCH 128
#define HW 3136            // 56*56
#define BATCH 64
#define NPC (BATCH * HW)   // 200704 elements per channel
#define NBINS 2048
#define GROUPS 8           // blocks per channel in stats phase
#define BPG (BATCH / GROUPS)
#define NBLK (CCH * GROUPS)  // 1024 blocks

typedef float f4v __attribute__((ext_vector_type(4)));

// workspace layout (no zero-init needed anywhere):
//   uint histp[NBLK][NBINS/2]  (u16x2 packed)   = 4 MB
//   float sums[2][NBLK]                         = 8 KB
//   float scale_shift[2*CCH]                    = 1 KB
#define HISTA_BYTES (NBLK * (NBINS / 2) * 4)
#define SUMSA_OFF   HISTA_BYTES
#define SCSHA_OFF   (SUMSA_OFF + 2 * NBLK * 4)
#define NEEDA       (SCSHA_OFF + 2 * CCH * 4)

// ---------------- phase bodies (shared by fused + fallback kernels) ----------------

__device__ __forceinline__ void phase_stats(const float* __restrict__ x,
                                            unsigned int* __restrict__ histp,
                                            float* __restrict__ sums,
                                            int blk, unsigned int* lh,
                                            float* ws_s, float* ws_ss) {
    const int c = blk / GROUPS;
    const int g = blk % GROUPS;

    for (int i = threadIdx.x; i < NBINS; i += 256) lh[i] = 0;
    __syncthreads();

    float s = 0.f, ss = 0.f;
    for (int bb = 0; bb < BPG; ++bb) {
        const int b = g * BPG + bb;
        const float4* p = (const float4*)(x + (size_t)(b * CCH + c) * HW);
        for (int i = threadIdx.x; i < HW / 4; i += 256) {
            float4 v = p[i];
            float e[4] = {v.x, v.y, v.z, v.w};
#pragma unroll
            for (int j = 0; j < 4; ++j) {
                float vv = e[j];
                s += vv;
                ss = fmaf(vv, vv, ss);
                int bin = (int)fmaf(vv, 128.f, 1024.f);  // (v+8)*NBINS/16
                bin = bin < 0 ? 0 : (bin > NBINS - 1 ? NBINS - 1 : bin);
                atomicAdd(&lh[bin], 1u);
            }
        }
    }
    __syncthreads();

    // flush histogram: pack two u16 counts per u32, plain stores (block owns its slice)
    unsigned int* dst = histp + (size_t)blk * (NBINS / 2);
    for (int i = threadIdx.x; i < NBINS / 2; i += 256) {
        unsigned int lo = lh[2 * i], hi = lh[2 * i + 1];
        dst[i] = lo | (hi << 16);  // per-group bin counts <= 25088 < 65536
    }

    for (int off = 32; off; off >>= 1) {
        s += __shfl_down(s, off);
        ss += __shfl_down(ss, off);
    }
    const int lane = threadIdx.x & 63, wid = threadIdx.x >> 6;
    if (lane == 0) { ws_s[wid] = s; ws_ss[wid] = ss; }
    __syncthreads();
    if (threadIdx.x == 0) {
        sums[blk] = ws_s[0] + ws_s[1] + ws_s[2] + ws_s[3];
        sums[NBLK + blk] = ws_ss[0] + ws_ss[1] + ws_ss[2] + ws_ss[3];
    }
}

__device__ __forceinline__ void phase_finalize(const unsigned int* __restrict__ histp,
                                               const float* __restrict__ sums,
                                               const float* __restrict__ weight,
                                               const float* __restrict__ bias,
                                               const float* __restrict__ smean,
                                               const float* __restrict__ svar,
                                               float* __restrict__ scale_shift,
                                               int c, unsigned int* lh,
                                               unsigned int* chunk) {
    const int t = threadIdx.x;

    // merge the 8 group slices (packed u16x2)
    for (int p = t; p < NBINS / 2; p += 256) {
        unsigned int lo = 0, hi = 0;
#pragma unroll
        for (int g = 0; g < GROUPS; ++g) {
            unsigned int v = histp[(size_t)(c * GROUPS + g) * (NBINS / 2) + p];
            lo += v & 0xFFFFu;
            hi += v >> 16;
        }
        lh[2 * p] = lo;
        lh[2 * p + 1] = hi;
    }
    __syncthreads();

    unsigned int cs = 0;
    for (int j = 0; j < 8; ++j) cs += lh[t * 8 + j];
    chunk[t] = cs;
    __syncthreads();

    if (t == 0) {
        const unsigned int target = (NPC - 1) / 2 + 1;  // 1-indexed rank of lower median
        unsigned int cum = 0;
        int ch = 0;
        for (int i = 0; i < 256; ++i) {
            if (cum + chunk[i] >= target) { ch = i; break; }
            cum += chunk[i];
        }
        int bin = ch * 8;
        for (int j = 0; j < 8; ++j) {
            unsigned int hv = lh[ch * 8 + j];
            if (cum + hv >= target) { bin = ch * 8 + j; break; }
            cum += hv;
        }
        const unsigned int cnt = lh[bin];
        const unsigned int r = target - cum;  // 1..cnt
        const float width = 16.f / NBINS;
        const float lo = -8.f + bin * width;
        const float m = lo + width * (((float)r - 0.5f) / (float)cnt);

        float sum = 0.f, sumsq = 0.f;
#pragma unroll
        for (int g = 0; g < GROUPS; ++g) {
            sum += sums[c * GROUPS + g];
            sumsq += sums[NBLK + c * GROUPS + g];
        }
        const float n = (float)NPC;
        const float bvar = sumsq / n - 2.f * m * (sum / n) + m * m;
        const float mean = 0.9f * smean[c] + 0.1f * m;
        const float var = 0.9f * svar[c] + 0.1f * bvar;
        const float inv = rsqrtf(var + 1e-5f);
        const float sc = inv * weight[c];
        scale_shift[c] = sc;
        scale_shift[CCH + c] = bias[c] - mean * sc;
    }
}

__device__ __forceinline__ void phase_norm(const float* __restrict__ x,
                                           const float* __restrict__ ss,
                                           float* __restrict__ out, int blk) {
    // same slab->block mapping as phase_stats for L2 locality
    const int c = blk / GROUPS;
    const int g = blk % GROUPS;
    const float sc = ss[c];
    const float sh = ss[CCH + c];
    for (int bb = 0; bb < BPG; ++bb) {
        const int b = g * BPG + bb;
        const size_t base = (size_t)(b * CCH + c) * HW;
        const f4v* px = (const f4v*)(x + base);
        f4v* po = (f4v*)(out + base);
        for (int i = threadIdx.x; i < HW / 4; i += 256) {
            f4v v = px[i];
            f4v r;
            r.x = fmaf(v.x, sc, sh);
            r.y = fmaf(v.y, sc, sh);
            r.z = fmaf(v.z, sc, sh);
            r.w = fmaf(v.w, sc, sh);
            __builtin_nontemporal_store(r, &po[i]);  // don't evict x from L3
        }
    }
}

// ---------------- fused cooperative kernel ----------------

__global__ __launch_bounds__(256, 4) void rmbn_fused(const float* __restrict__ x,
                                                     unsigned int* __restrict__ histp,
                                                     float* __restrict__ sums,
                                                     const float* __restrict__ weight,
                                                     const float* __restrict__ bias,
                                                     const float* __restrict__ smean,
                                                     const float* __restrict__ svar,
                                                     float* __restrict__ scsh,
                                                     float* __restrict__ out) {
    __shared__ unsigned int lh[NBINS];
    __shared__ unsigned int chunk[256];
    __shared__ float ws_s[4], ws_ss[4];

    cg::grid_group grid = cg::this_grid();
    const int blk = blockIdx.x;

    phase_stats(x, histp, sums, blk, lh, ws_s, ws_ss);

    grid.sync();

    if (blk < CCH) {
        __syncthreads();  // lh reuse safety within block
        phase_finalize(histp, sums, weight, bias, smean, svar, scsh, blk, lh, chunk);
    }

    grid.sync();

    phase_norm(x, scsh, out, blk);
}

// ---------------- fallback: 3 separate kernels (same phases) ----------------

__global__ __launch_bounds__(256) void rmbn_stats_k(const float* __restrict__ x,
                                                    unsigned int* __restrict__ histp,
                                                    float* __restrict__ sums) {
    __shared__ unsigned int lh[NBINS];
    __shared__ float ws_s[4], ws_ss[4];
    phase_stats(x, histp, sums, blockIdx.x, lh, ws_s, ws_ss);
}

__global__ __launch_bounds__(256) void rmbn_finalize_k(const unsigned int* __restrict__ histp,
                                                       const float* __restrict__ sums,
                                                       const float* __restrict__ weight,
                                                       const float* __restrict__ bias,
                                                       const float* __restrict__ smean,
                                                       const float* __restrict__ svar,
                                                       float* __restrict__ scsh) {
    __shared__ unsigned int lh[NBINS];
    __shared__ unsigned int chunk[256];
    phase_finalize(histp, sums, weight, bias, smean, svar, scsh, blockIdx.x, lh, chunk);
}

__global__ __launch_bounds__(256) void rmbn_norm_k(const float* __restrict__ x,
                                                   const float* __restrict__ ss,
                                                   float* __restrict__ out) {
    phase_norm(x, ss, out, blockIdx.x);
}

extern "C" void kernel_launch(void* const* d_in, const int* in_sizes, int n_in,
                              void* d_out, int out_size, void* d_ws, size_t ws_size,
                              hipStream_t stream) {
    const float* x = (const float*)d_in[0];
    const float* weight = (const float*)d_in[1];
    const float* bias = (const float*)d_in[2];
    const float* smean = (const float*)d_in[3];
    const float* svar = (const float*)d_in[4];
    float* out = (float*)d_out;
    unsigned char* ws = (unsigned char*)d_ws;

    unsigned int* histp = (unsigned int*)ws;
    float* sums = (float*)(ws + SUMSA_OFF);
    float* scsh = (float*)(ws + SCSHA_OFF);

    void* args[] = {(void*)&x, (void*)&histp, (void*)&sums, (void*)&weight,
                    (void*)&bias, (void*)&smean, (void*)&svar, (void*)&scsh,
                    (void*)&out};
    hipError_t e = hipLaunchCooperativeKernel(reinterpret_cast<void*>(rmbn_fused),
                                              dim3(NBLK), dim3(256), args, 0, stream);
    if (e != hipSuccess) {
        // fallback: 3-kernel path, same algorithm, no memset needed
        rmbn_stats_k<<<NBLK, 256, 0, stream>>>(x, histp, sums);
        rmbn_finalize_k<<<CCH, 256, 0, stream>>>(histp, sums, weight, bias, smean, svar, scsh);
        rmbn_norm_k<<<NBLK, 256, 0, stream>>>(x, scsh, out);
    }
}

// Round 4
// 65.516 us; speedup vs baseline: 3.8281x; 3.8281x over previous
//
#include <hip/hip_runtime.h>

#define CCH 128
#define HW 3136            // 56*56
#define BATCH 64
#define NPC (BATCH * HW)   // 200704 elements per channel
#define NBINS 2048
#define GROUPS 8           // blocks per channel
#define BPG (BATCH / GROUPS)
#define NBLK (CCH * GROUPS)  // 1024 blocks

typedef float f4v __attribute__((ext_vector_type(4)));

// workspace layout (no zero-init needed anywhere):
//   uint histp[NBLK][NBINS/2]  (u16x2 packed)   = 4 MB
//   float sums[2][NBLK]                         = 8 KB
#define HISTA_BYTES (NBLK * (NBINS / 2) * 4)
#define SUMSA_OFF   HISTA_BYTES

// ---------------- kernel 1: per-(channel,group) stats ----------------

__global__ __launch_bounds__(256) void rmbn_stats(const float* __restrict__ x,
                                                  unsigned int* __restrict__ histp,
                                                  float* __restrict__ sums) {
    const int blk = blockIdx.x;
    const int c = blk / GROUPS;
    const int g = blk % GROUPS;

    __shared__ unsigned int lh[NBINS];
    __shared__ float ws_s[4], ws_ss[4];

    for (int i = threadIdx.x; i < NBINS; i += 256) lh[i] = 0;
    __syncthreads();

    float s = 0.f, ss = 0.f;
    for (int bb = 0; bb < BPG; ++bb) {
        const int b = g * BPG + bb;
        const float4* p = (const float4*)(x + (size_t)(b * CCH + c) * HW);
        for (int i = threadIdx.x; i < HW / 4; i += 256) {
            float4 v = p[i];
            float e[4] = {v.x, v.y, v.z, v.w};
#pragma unroll
            for (int j = 0; j < 4; ++j) {
                float vv = e[j];
                s += vv;
                ss = fmaf(vv, vv, ss);
                int bin = (int)fmaf(vv, 128.f, 1024.f);  // (v+8)*NBINS/16
                bin = bin < 0 ? 0 : (bin > NBINS - 1 ? NBINS - 1 : bin);
                atomicAdd(&lh[bin], 1u);
            }
        }
    }
    __syncthreads();

    // flush histogram: pack two u16 counts per u32, plain stores (block owns slice)
    unsigned int* dst = histp + (size_t)blk * (NBINS / 2);
    for (int i = threadIdx.x; i < NBINS / 2; i += 256) {
        unsigned int lo = lh[2 * i], hi = lh[2 * i + 1];
        dst[i] = lo | (hi << 16);  // per-group bin counts <= 25088 < 65536
    }

    for (int off = 32; off; off >>= 1) {
        s += __shfl_down(s, off);
        ss += __shfl_down(ss, off);
    }
    const int lane = threadIdx.x & 63, wid = threadIdx.x >> 6;
    if (lane == 0) { ws_s[wid] = s; ws_ss[wid] = ss; }
    __syncthreads();
    if (threadIdx.x == 0) {
        sums[blk] = ws_s[0] + ws_s[1] + ws_s[2] + ws_s[3];
        sums[NBLK + blk] = ws_ss[0] + ws_ss[1] + ws_ss[2] + ws_ss[3];
    }
}

// ---------------- kernel 2: redundant per-block finalize + norm ----------------
// Each of the 1024 blocks recomputes its channel's median/scale from the global
// histogram slices (identical deterministic computation across the channel's 8
// blocks -> no sync needed), then normalizes its 8 slabs.

__global__ __launch_bounds__(256) void rmbn_norm_fin(const float* __restrict__ x,
                                                     const unsigned int* __restrict__ histp,
                                                     const float* __restrict__ sums,
                                                     const float* __restrict__ weight,
                                                     const float* __restrict__ bias,
                                                     const float* __restrict__ smean,
                                                     const float* __restrict__ svar,
                                                     float* __restrict__ out) {
    const int blk = blockIdx.x;
    const int c = blk / GROUPS;
    const int g = blk % GROUPS;
    const int t = threadIdx.x;

    __shared__ unsigned int lh[NBINS];
    __shared__ unsigned int chunk[256];
    __shared__ float sh_sc, sh_sh;

    // merge the channel's 8 group slices (packed u16x2)
    for (int p = t; p < NBINS / 2; p += 256) {
        unsigned int lo = 0, hi = 0;
#pragma unroll
        for (int gg = 0; gg < GROUPS; ++gg) {
            unsigned int v = histp[(size_t)(c * GROUPS + gg) * (NBINS / 2) + p];
            lo += v & 0xFFFFu;
            hi += v >> 16;
        }
        lh[2 * p] = lo;
        lh[2 * p + 1] = hi;
    }
    __syncthreads();

    unsigned int cs = 0;
#pragma unroll
    for (int j = 0; j < 8; ++j) cs += lh[t * 8 + j];
    chunk[t] = cs;
    __syncthreads();

    if (t == 0) {
        const unsigned int target = (NPC - 1) / 2 + 1;  // 1-indexed rank of lower median
        unsigned int cum = 0;
        int ch = 0;
        for (int i = 0; i < 256; ++i) {
            if (cum + chunk[i] >= target) { ch = i; break; }
            cum += chunk[i];
        }
        int bin = ch * 8;
        for (int j = 0; j < 8; ++j) {
            unsigned int hv = lh[ch * 8 + j];
            if (cum + hv >= target) { bin = ch * 8 + j; break; }
            cum += hv;
        }
        const unsigned int cnt = lh[bin];
        const unsigned int r = target - cum;  // 1..cnt
        const float width = 16.f / NBINS;
        const float lo = -8.f + bin * width;
        const float m = lo + width * (((float)r - 0.5f) / (float)cnt);

        float sum = 0.f, sumsq = 0.f;
#pragma unroll
        for (int gg = 0; gg < GROUPS; ++gg) {
            sum += sums[c * GROUPS + gg];
            sumsq += sums[NBLK + c * GROUPS + gg];
        }
        const float n = (float)NPC;
        const float bvar = sumsq / n - 2.f * m * (sum / n) + m * m;
        const float mean = 0.9f * smean[c] + 0.1f * m;
        const float var = 0.9f * svar[c] + 0.1f * bvar;
        const float inv = rsqrtf(var + 1e-5f);
        const float sc = inv * weight[c];
        sh_sc = sc;
        sh_sh = bias[c] - mean * sc;
    }
    __syncthreads();

    const float sc = sh_sc;
    const float sh = sh_sh;

    for (int bb = 0; bb < BPG; ++bb) {
        const int b = g * BPG + bb;
        const size_t base = (size_t)(b * CCH + c) * HW;
        const f4v* px = (const f4v*)(x + base);
        f4v* po = (f4v*)(out + base);
        for (int i = threadIdx.x; i < HW / 4; i += 256) {
            f4v v = px[i];
            f4v r;
            r.x = fmaf(v.x, sc, sh);
            r.y = fmaf(v.y, sc, sh);
            r.z = fmaf(v.z, sc, sh);
            r.w = fmaf(v.w, sc, sh);
            __builtin_nontemporal_store(r, &po[i]);  // don't pollute caches with out
        }
    }
}

extern "C" void kernel_launch(void* const* d_in, const int* in_sizes, int n_in,
                              void* d_out, int out_size, void* d_ws, size_t ws_size,
                              hipStream_t stream) {
    const float* x = (const float*)d_in[0];
    const float* weight = (const float*)d_in[1];
    const float* bias = (const float*)d_in[2];
    const float* smean = (const float*)d_in[3];
    const float* svar = (const float*)d_in[4];
    float* out = (float*)d_out;
    unsigned char* ws = (unsigned char*)d_ws;

    unsigned int* histp = (unsigned int*)ws;
    float* sums = (float*)(ws + SUMSA_OFF);

    rmbn_stats<<<NBLK, 256, 0, stream>>>(x, histp, sums);
    rmbn_norm_fin<<<NBLK, 256, 0, stream>>>(x, histp, sums, weight, bias, smean, svar, out);
}